// Round 7
// baseline (338.703 us; speedup 1.0000x reference)
//
#include <hip/hip_runtime.h>
#include <hip/hip_fp16.h>

#define BN_EPS 1e-5f

typedef int      v4i __attribute__((ext_vector_type(4)));
typedef unsigned v4u __attribute__((ext_vector_type(4)));
typedef unsigned v2u __attribute__((ext_vector_type(2)));
typedef float    v4f __attribute__((ext_vector_type(4)));

__device__ __forceinline__ __half2 u2h2(unsigned u) {
    union { unsigned u; __half2 h; } c; c.u = u; return c.h;
}
__device__ __forceinline__ unsigned h22u(__half2 h) {
    union { unsigned u; __half2 h; } c; c.h = h; return c.u;
}

// ---------------------------------------------------------------------------
// K0: pack f32 [N][12] rows into fp16 [N][16] (32 B rows, line-aligned,
// zero-padded).
// ---------------------------------------------------------------------------
__global__ void k_pack_half(const float* __restrict__ emb,
                            __half2* __restrict__ hemb, int N) {
    int n = blockIdx.x * blockDim.x + threadIdx.x;
    if (n >= N) return;
    const float* r = emb + (size_t)n * 12;
    union { int4 v[2]; __half2 h[8]; } u;
    #pragma unroll
    for (int k = 0; k < 6; ++k) u.h[k] = __floats2half2_rn(r[2 * k], r[2 * k + 1]);
    u.h[6] = __floats2half2_rn(0.f, 0.f);
    u.h[7] = u.h[6];
    int4* dst = (int4*)(hemb + (size_t)n * 8);
    dst[0] = u.v[0];
    dst[1] = u.v[1];
}

// dot of two 12-half rows given as 6 packed uints each
__device__ __forceinline__ float rowdot12u(const unsigned* a, const unsigned* b) {
    float dot = 0.f;
    #pragma unroll
    for (int k = 0; k < 6; ++k) {
        float2 fa = __half22float2(u2h2(a[k]));
        float2 fb = __half22float2(u2h2(b[k]));
        dot = fmaf(fa.x, fb.x, dot);
        dot = fmaf(fa.y, fb.y, dot);
    }
    return dot;
}

__device__ __forceinline__ float rowdot(const int4* __restrict__ a,
                                        const int4* __restrict__ b) {
    union U { int4 v; unsigned u[4]; };
    U a0{a[0]}, a1{a[1]}, b0{b[0]}, b1{b[1]};
    unsigned au[6] = {a0.u[0], a0.u[1], a0.u[2], a0.u[3], a1.u[0], a1.u[1]};
    unsigned bu[6] = {b0.u[0], b0.u[1], b0.u[2], b0.u[3], b1.u[0], b1.u[1]};
    return rowdot12u(au, bu);
}

// ---------------------------------------------------------------------------
// PASS A: srow[e] = hs[gsrc[e]] (24 B fp16 row). Only the 3.2 MB hs table is
// hot -> fits each XCD's 4 MB L2 (compulsory-only HBM fetch). Output is a
// sequential NT stream. 4 edges/thread -> 96 B = 6 x int4 aligned stores.
// ---------------------------------------------------------------------------
__global__ __launch_bounds__(256) void k_gather_src(
        const __half2* __restrict__ hs,
        const int* __restrict__ gsrc,
        unsigned* __restrict__ srow,
        int E) {
    int e0 = (blockIdx.x * blockDim.x + threadIdx.x) * 4;
    if (e0 + 4 <= E) {
        v4i s4 = __builtin_nontemporal_load((const v4i*)(gsrc + e0));
        int is[4] = {s4.x, s4.y, s4.z, s4.w};
        unsigned r[24];
        #pragma unroll
        for (int k = 0; k < 4; ++k) {
            const int4* row = (const int4*)(hs + (size_t)is[k] * 8);
            union U { int4 v; unsigned u[4]; };
            U a{row[0]};
            int2 b = ((const int2*)row)[2];
            r[6 * k + 0] = a.u[0]; r[6 * k + 1] = a.u[1];
            r[6 * k + 2] = a.u[2]; r[6 * k + 3] = a.u[3];
            r[6 * k + 4] = (unsigned)b.x; r[6 * k + 5] = (unsigned)b.y;
        }
        v4u* dst = (v4u*)(srow + (size_t)e0 * 6);
        #pragma unroll
        for (int j = 0; j < 6; ++j) {
            v4u w = {r[4 * j], r[4 * j + 1], r[4 * j + 2], r[4 * j + 3]};
            __builtin_nontemporal_store(w, dst + j);
        }
    } else {
        for (int e = e0; e < E; ++e) {
            const unsigned* row = (const unsigned*)(hs + (size_t)gsrc[e] * 8);
            for (int j = 0; j < 6; ++j) srow[(size_t)e * 6 + j] = row[j];
        }
    }
}

// ---------------------------------------------------------------------------
// PASS B: stream srow back (sequential NT), gather hd[gdst[e]] (lone 3.2 MB
// table -> L2-resident), dot, fp16 like store + block-reduced stats.
// ---------------------------------------------------------------------------
__global__ __launch_bounds__(256) void k_dot_stats(
        const __half2* __restrict__ hd,
        const unsigned* __restrict__ srow,
        const int* __restrict__ gdst,
        __half* __restrict__ like,
        double* __restrict__ acc,   // acc[0]=sum, acc[1]=sumsq
        int E) {
    int e0 = (blockIdx.x * blockDim.x + threadIdx.x) * 4;
    float lsum = 0.f, lsq = 0.f;
    if (e0 + 4 <= E) {
        v4i d4 = __builtin_nontemporal_load((const v4i*)(gdst + e0));
        int id[4] = {d4.x, d4.y, d4.z, d4.w};
        const v4u* sp = (const v4u*)(srow + (size_t)e0 * 6);
        unsigned r[24];
        #pragma unroll
        for (int j = 0; j < 6; ++j) {
            v4u c = __builtin_nontemporal_load(sp + j);
            r[4 * j] = c.x; r[4 * j + 1] = c.y;
            r[4 * j + 2] = c.z; r[4 * j + 3] = c.w;
        }
        float dv[4];
        #pragma unroll
        for (int k = 0; k < 4; ++k) {
            const int4* row = (const int4*)(hd + (size_t)id[k] * 8);
            union U { int4 v; unsigned u[4]; };
            U b0{row[0]};
            int2 b1 = ((const int2*)row)[2];
            unsigned bu[6] = {b0.u[0], b0.u[1], b0.u[2], b0.u[3],
                              (unsigned)b1.x, (unsigned)b1.y};
            dv[k] = rowdot12u(&r[6 * k], bu);
            lsum += dv[k];
            lsq  = fmaf(dv[k], dv[k], lsq);
        }
        v2u o;
        o.x = h22u(__floats2half2_rn(dv[0], dv[1]));
        o.y = h22u(__floats2half2_rn(dv[2], dv[3]));
        __builtin_nontemporal_store(o, (v2u*)(like + e0));
    } else {
        for (int e = e0; e < E; ++e) {
            const int4* row = (const int4*)(hd + (size_t)gdst[e] * 8);
            union U { int4 v; unsigned u[4]; };
            U b0{row[0]};
            int2 b1 = ((const int2*)row)[2];
            unsigned bu[6] = {b0.u[0], b0.u[1], b0.u[2], b0.u[3],
                              (unsigned)b1.x, (unsigned)b1.y};
            float d = rowdot12u(srow + (size_t)e * 6, bu);
            like[e] = __float2half(d);
            lsum += d;
            lsq  += d * d;
        }
    }
    for (int off = 32; off > 0; off >>= 1) {
        lsum += __shfl_down(lsum, off);
        lsq  += __shfl_down(lsq, off);
    }
    __shared__ float ssum[4], ssq[4];
    int wave = threadIdx.x >> 6;
    int lane = threadIdx.x & 63;
    if (lane == 0) { ssum[wave] = lsum; ssq[wave] = lsq; }
    __syncthreads();
    if (threadIdx.x == 0) {
        float ts = 0.f, tq = 0.f;
        for (int i = 0; i < 4; ++i) { ts += ssum[i]; tq += ssq[i]; }
        atomicAdd(&acc[0], (double)ts);
        atomicAdd(&acc[1], (double)tq);
    }
}

// Fused single-pass fallback (round-5 style) if ws can't hold srow.
__global__ __launch_bounds__(256) void k_dot_fused(
        const __half2* __restrict__ hs,
        const __half2* __restrict__ hd,
        const int* __restrict__ gsrc,
        const int* __restrict__ gdst,
        __half* __restrict__ like,
        double* __restrict__ acc,
        int E) {
    int e0 = (blockIdx.x * blockDim.x + threadIdx.x) * 8;
    float lsum = 0.f, lsq = 0.f;
    if (e0 + 8 <= E) {
        v4i s0 = __builtin_nontemporal_load((const v4i*)(gsrc + e0));
        v4i s1 = __builtin_nontemporal_load((const v4i*)(gsrc + e0 + 4));
        v4i d0 = __builtin_nontemporal_load((const v4i*)(gdst + e0));
        v4i d1 = __builtin_nontemporal_load((const v4i*)(gdst + e0 + 4));
        int is[8] = {s0.x, s0.y, s0.z, s0.w, s1.x, s1.y, s1.z, s1.w};
        int id[8] = {d0.x, d0.y, d0.z, d0.w, d1.x, d1.y, d1.z, d1.w};
        float dv[8];
        #pragma unroll
        for (int k = 0; k < 8; ++k) {
            dv[k] = rowdot((const int4*)(hs + (size_t)is[k] * 8),
                           (const int4*)(hd + (size_t)id[k] * 8));
            lsum += dv[k];
            lsq  = fmaf(dv[k], dv[k], lsq);
        }
        v4u o;
        o.x = h22u(__floats2half2_rn(dv[0], dv[1]));
        o.y = h22u(__floats2half2_rn(dv[2], dv[3]));
        o.z = h22u(__floats2half2_rn(dv[4], dv[5]));
        o.w = h22u(__floats2half2_rn(dv[6], dv[7]));
        __builtin_nontemporal_store(o, (v4u*)(like + e0));
    } else {
        for (int e = e0; e < E; ++e) {
            float d = rowdot((const int4*)(hs + (size_t)gsrc[e] * 8),
                             (const int4*)(hd + (size_t)gdst[e] * 8));
            like[e] = __float2half(d);
            lsum += d;
            lsq  += d * d;
        }
    }
    for (int off = 32; off > 0; off >>= 1) {
        lsum += __shfl_down(lsum, off);
        lsq  += __shfl_down(lsq, off);
    }
    __shared__ float ssum[4], ssq[4];
    int wave = threadIdx.x >> 6;
    int lane = threadIdx.x & 63;
    if (lane == 0) { ssum[wave] = lsum; ssq[wave] = lsq; }
    __syncthreads();
    if (threadIdx.x == 0) {
        float ts = 0.f, tq = 0.f;
        for (int i = 0; i < 4; ++i) { ts += ssum[i]; tq += ssq[i]; }
        atomicAdd(&acc[0], (double)ts);
        atomicAdd(&acc[1], (double)tq);
    }
}

// ---------------------------------------------------------------------------
// K2: fold batch stats + bn affine into (scale, shift).
// ---------------------------------------------------------------------------
__global__ void k_params(const double* __restrict__ acc,
                         const float* __restrict__ bnw,
                         const float* __restrict__ bnb,
                         float* __restrict__ params,
                         int E) {
    double mean = acc[0] / (double)E;
    double var  = acc[1] / (double)E - mean * mean;
    float invstd = rsqrtf((float)var + BN_EPS);
    float scale = bnw[0] * invstd;
    params[0] = scale;
    params[1] = bnb[0] - (float)mean * scale;
}

// ---------------------------------------------------------------------------
// K3: LDS-privatized segment sum, dynamic-LDS bucket (100 KB -> P=4 passes),
// NT streaming loads, slab output via NT stores, no global atomics.
// ---------------------------------------------------------------------------
__global__ __launch_bounds__(512) void k_bucket_scatter(
        const __half* __restrict__ like,
        const int* __restrict__ gsrc,
        const float* __restrict__ params,
        float* __restrict__ slab,   // [(p*G + g) * bucket]
        int E, int G, int bucket) {
    extern __shared__ float sm[];
    const int g  = blockIdx.x;
    const int p  = blockIdx.y;
    const int lo = p * bucket;

    for (int i = threadIdx.x; i < bucket; i += blockDim.x) sm[i] = 0.f;
    __syncthreads();

    const float scale = params[0];
    const float shift = params[1];

    int per = (E + G - 1) / G;
    per = (per + 3) & ~3;
    const int s0 = g * per;
    const int s1 = min(s0 + per, E);

    for (int e = s0 + (int)threadIdx.x * 4; e < s1; e += (int)blockDim.x * 4) {
        if (e + 4 <= s1) {
            v4i n4 = __builtin_nontemporal_load((const v4i*)(gsrc + e));
            v2u l2 = __builtin_nontemporal_load((const v2u*)(like + e));
            float2 fa = __half22float2(u2h2(l2.x));
            float2 fb = __half22float2(u2h2(l2.y));
            unsigned o0 = (unsigned)(n4.x - lo);
            unsigned o1 = (unsigned)(n4.y - lo);
            unsigned o2 = (unsigned)(n4.z - lo);
            unsigned o3 = (unsigned)(n4.w - lo);
            if (o0 < (unsigned)bucket) atomicAdd(&sm[o0], __expf(fmaf(fa.x, scale, shift)));
            if (o1 < (unsigned)bucket) atomicAdd(&sm[o1], __expf(fmaf(fa.y, scale, shift)));
            if (o2 < (unsigned)bucket) atomicAdd(&sm[o2], __expf(fmaf(fb.x, scale, shift)));
            if (o3 < (unsigned)bucket) atomicAdd(&sm[o3], __expf(fmaf(fb.y, scale, shift)));
        } else {
            for (int k = 0; e + k < s1; ++k) {
                unsigned o = (unsigned)(gsrc[e + k] - lo);
                if (o < (unsigned)bucket)
                    atomicAdd(&sm[o], __expf(fmaf(__half2float(like[e + k]), scale, shift)));
            }
        }
    }
    __syncthreads();

    float* dst = slab + ((size_t)p * G + g) * bucket;
    for (int i = threadIdx.x; i < bucket; i += blockDim.x)
        __builtin_nontemporal_store(sm[i], dst + i);
}

// ---------------------------------------------------------------------------
// K3b: fold slabs: denom[n] = sum_g slab[(p(n)*G + g)*bucket + n%bucket]
// ---------------------------------------------------------------------------
__global__ void k_fold(const float* __restrict__ slab,
                       float* __restrict__ denom, int N, int G, int bucket) {
    int n = blockIdx.x * blockDim.x + threadIdx.x;
    if (n >= N) return;
    int p   = n / bucket;
    int off = n - p * bucket;
    const float* s = slab + (size_t)p * G * bucket + off;
    float acc = 0.f;
    for (int g = 0; g < G; ++g)
        acc += __builtin_nontemporal_load(s + (size_t)g * bucket);
    denom[n] = acc;
}

// ---------------------------------------------------------------------------
// K4: out[e] = exp(like*scale+shift) / (1e-12 + denom[gsrc[e]])
// ---------------------------------------------------------------------------
__global__ void k_normalize(const __half* __restrict__ like,
                            const int* __restrict__ gsrc,
                            const float* __restrict__ params,
                            const float* __restrict__ denom,
                            float* __restrict__ out,
                            int E) {
    const float scale = params[0];
    const float shift = params[1];
    int e = (blockIdx.x * blockDim.x + threadIdx.x) * 4;
    if (e + 4 <= E) {
        v4i n4 = __builtin_nontemporal_load((const v4i*)(gsrc + e));
        v2u l2 = __builtin_nontemporal_load((const v2u*)(like + e));
        float2 fa = __half22float2(u2h2(l2.x));
        float2 fb = __half22float2(u2h2(l2.y));
        v4f o;
        o.x = __expf(fmaf(fa.x, scale, shift)) / (1e-12f + denom[n4.x]);
        o.y = __expf(fmaf(fa.y, scale, shift)) / (1e-12f + denom[n4.y]);
        o.z = __expf(fmaf(fb.x, scale, shift)) / (1e-12f + denom[n4.z]);
        o.w = __expf(fmaf(fb.y, scale, shift)) / (1e-12f + denom[n4.w]);
        __builtin_nontemporal_store(o, (v4f*)(out + e));
    } else {
        for (; e < E; ++e)
            out[e] = __expf(fmaf(__half2float(like[e]), scale, shift)) /
                     (1e-12f + denom[gsrc[e]]);
    }
}

// Fallback (agent-scope atomics) if ws can't hold the slab.
__global__ void k_exp_scatter_agent(const __half* __restrict__ like,
                                    const int* __restrict__ gsrc,
                                    const float* __restrict__ params,
                                    float* __restrict__ denom,
                                    int E) {
    float scale = params[0];
    float shift = params[1];
    for (int e = blockIdx.x * blockDim.x + threadIdx.x; e < E;
         e += gridDim.x * blockDim.x) {
        atomicAdd(&denom[gsrc[e]],
                  __expf(fmaf(__half2float(like[e]), scale, shift)));
    }
}

extern "C" void kernel_launch(void* const* d_in, const int* in_sizes, int n_in,
                              void* d_out, int out_size, void* d_ws, size_t ws_size,
                              hipStream_t stream) {
    const float* src_emb = (const float*)d_in[0];
    const float* dst_emb = (const float*)d_in[1];
    const float* bnw     = (const float*)d_in[2];
    const float* bnb     = (const float*)d_in[3];
    const int*   gsrc    = (const int*)d_in[4];
    const int*   gdst    = (const int*)d_in[5];

    const int E = in_sizes[4];           // 3,200,000 edges
    const int N = in_sizes[0] / 12;      // 100,000 nodes
    float* out = (float*)d_out;

    const int bucket = 25000;            // 100 KB dynamic LDS
    const int P = (N + bucket - 1) / bucket;   // 4 passes

    // workspace layout (64B-aligned regions):
    //   acc(16)|params(16)|pad | like(2E) | denom(4N) | hs(32N) | hd(32N) |
    //   shared region: max(srow 24E, slab P*G*bucket*4)  (live ranges disjoint)
    char* ws = (char*)d_ws;
    double*  acc    = (double*)ws;
    float*   params = (float*)(ws + 16);
    size_t   off    = 64;
    __half*  like   = (__half*)(ws + off);  off += ((size_t)E * 2 + 63) & ~(size_t)63;
    float*   denom  = (float*)(ws + off);   off += ((size_t)N * 4 + 63) & ~(size_t)63;
    __half2* hs     = (__half2*)(ws + off); off += ((size_t)N * 32 + 63) & ~(size_t)63;
    __half2* hd     = (__half2*)(ws + off); off += ((size_t)N * 32 + 63) & ~(size_t)63;
    unsigned* srow  = (unsigned*)(ws + off);
    float*    slab  = (float*)(ws + off);

    size_t rem = (ws_size > off) ? ws_size - off : 0;
    size_t srow_bytes = (size_t)E * 24;
    bool split = (rem >= srow_bytes + 64);

    size_t region = split ? (rem > srow_bytes ? rem : srow_bytes) : rem;
    // slab shares the region with srow (disjoint live ranges); if split, the
    // slab must ALSO fit in rem.
    int G = 0;
    for (int cand = 64; cand >= 8; cand >>= 1) {
        if ((size_t)P * cand * bucket * 4 <= rem) { G = cand; break; }
    }
    if (split && (size_t)P * (G > 0 ? G : 8) * bucket * 4 > rem) split = false;
    (void)region;

    const int block = 256;

    hipMemsetAsync(ws, 0, 32, stream);

    k_pack_half<<<(N + block - 1) / block, block, 0, stream>>>(src_emb, hs, N);
    k_pack_half<<<(N + block - 1) / block, block, 0, stream>>>(dst_emb, hd, N);

    if (split) {
        int t4 = (E + 3) / 4;
        int b4 = (t4 + block - 1) / block;
        k_gather_src<<<b4, block, 0, stream>>>(hs, gsrc, srow, E);
        k_dot_stats<<<b4, block, 0, stream>>>(hd, srow, gdst, like, acc, E);
    } else {
        int t8 = (E + 7) / 8;
        int b8 = (t8 + block - 1) / block;
        k_dot_fused<<<b8, block, 0, stream>>>(hs, hd, gsrc, gdst, like, acc, E);
    }

    k_params<<<1, 1, 0, stream>>>(acc, bnw, bnb, params, E);

    if (G > 0) {
        dim3 grid(G, P);
        k_bucket_scatter<<<grid, 512, (size_t)bucket * 4, stream>>>(
            like, gsrc, params, slab, E, G, bucket);
        k_fold<<<(N + block - 1) / block, block, 0, stream>>>(slab, denom, N,
                                                              G, bucket);
    } else {
        hipMemsetAsync(denom, 0, (size_t)N * 4, stream);
        int blocks = min((E + block - 1) / block, 4096);
        k_exp_scatter_agent<<<blocks, block, 0, stream>>>(like, gsrc, params,
                                                          denom, E);
    }

    k_normalize<<<(E / 4 + block - 1) / block, block, 0, stream>>>(
        like, gsrc, params, denom, out, E);
}

// Round 8
// 213.535 us; speedup vs baseline: 1.5862x; 1.5862x over previous
//
#include <hip/hip_runtime.h>
#include <hip/hip_fp16.h>

#define BN_EPS 1e-5f

typedef int      v4i __attribute__((ext_vector_type(4)));
typedef unsigned v4u __attribute__((ext_vector_type(4)));
typedef unsigned v2u __attribute__((ext_vector_type(2)));
typedef float    v4f __attribute__((ext_vector_type(4)));

__device__ __forceinline__ __half2 u2h2(unsigned u) {
    union { unsigned u; __half2 h; } c; c.u = u; return c.h;
}
__device__ __forceinline__ unsigned h22u(__half2 h) {
    union { unsigned u; __half2 h; } c; c.h = h; return c.u;
}

// ---------------------------------------------------------------------------
// K0: pack f32 [N][12] rows into fp16 [N][16] (32 B rows, line-aligned,
// zero-padded).
// ---------------------------------------------------------------------------
__global__ void k_pack_half(const float* __restrict__ emb,
                            __half2* __restrict__ hemb, int N) {
    int n = blockIdx.x * blockDim.x + threadIdx.x;
    if (n >= N) return;
    const float* r = emb + (size_t)n * 12;
    union { int4 v[2]; __half2 h[8]; } u;
    #pragma unroll
    for (int k = 0; k < 6; ++k) u.h[k] = __floats2half2_rn(r[2 * k], r[2 * k + 1]);
    u.h[6] = __floats2half2_rn(0.f, 0.f);
    u.h[7] = u.h[6];
    int4* dst = (int4*)(hemb + (size_t)n * 8);
    dst[0] = u.v[0];
    dst[1] = u.v[1];
}

// dot of two 12-half rows given as 6 packed uints each
__device__ __forceinline__ float rowdot12u(const unsigned* a, const unsigned* b) {
    float dot = 0.f;
    #pragma unroll
    for (int k = 0; k < 6; ++k) {
        float2 fa = __half22float2(u2h2(a[k]));
        float2 fb = __half22float2(u2h2(b[k]));
        dot = fmaf(fa.x, fb.x, dot);
        dot = fmaf(fa.y, fb.y, dot);
    }
    return dot;
}

__device__ __forceinline__ float rowdot(const int4* __restrict__ a,
                                        const int4* __restrict__ b) {
    union U { int4 v; unsigned u[4]; };
    U a0{a[0]}, a1{a[1]}, b0{b[0]}, b1{b[1]};
    unsigned au[6] = {a0.u[0], a0.u[1], a0.u[2], a0.u[3], a1.u[0], a1.u[1]};
    unsigned bu[6] = {b0.u[0], b0.u[1], b0.u[2], b0.u[3], b1.u[0], b1.u[1]};
    return rowdot12u(au, bu);
}

// ---------------------------------------------------------------------------
// PASS A: gather hs[gsrc[e]] (lone 3.2 MB table -> L2-resident, proven
// FETCH=19MB in r6) and write the 24 B fp16 rows as 6 SoA PLANES of 4 B:
// srow[j*Ep + e]. A wave's store of plane j covers 64 lanes x 4 edges x 4 B
// = 1024 contiguous bytes -> fully coalesced NT writes (fixes r6's 3.6x
// write inflation from the strided AoS layout).
// ---------------------------------------------------------------------------
__global__ __launch_bounds__(256) void k_gather_src(
        const __half2* __restrict__ hs,
        const int* __restrict__ gsrc,
        unsigned* __restrict__ srow,
        int E, int Ep) {
    int e0 = (blockIdx.x * blockDim.x + threadIdx.x) * 4;
    if (e0 + 4 <= E) {
        v4i s4 = __builtin_nontemporal_load((const v4i*)(gsrc + e0));
        int is[4] = {s4.x, s4.y, s4.z, s4.w};
        unsigned r[4][6];
        #pragma unroll
        for (int k = 0; k < 4; ++k) {
            const int4* row = (const int4*)(hs + (size_t)is[k] * 8);
            union U { int4 v; unsigned u[4]; };
            U a{row[0]};
            int2 b = ((const int2*)row)[2];
            r[k][0] = a.u[0]; r[k][1] = a.u[1];
            r[k][2] = a.u[2]; r[k][3] = a.u[3];
            r[k][4] = (unsigned)b.x; r[k][5] = (unsigned)b.y;
        }
        #pragma unroll
        for (int j = 0; j < 6; ++j) {
            v4u w = {r[0][j], r[1][j], r[2][j], r[3][j]};
            __builtin_nontemporal_store(w, (v4u*)(srow + (size_t)j * Ep + e0));
        }
    } else {
        for (int e = e0; e < E; ++e) {
            const unsigned* row = (const unsigned*)(hs + (size_t)gsrc[e] * 8);
            for (int j = 0; j < 6; ++j) srow[(size_t)j * Ep + e] = row[j];
        }
    }
}

// ---------------------------------------------------------------------------
// PASS B: stream the 6 srow planes back (coalesced NT), gather hd[gdst[e]]
// (lone table -> L2-resident), dot, fp16 like store + block-reduced stats.
// ---------------------------------------------------------------------------
__global__ __launch_bounds__(256) void k_dot_stats(
        const __half2* __restrict__ hd,
        const unsigned* __restrict__ srow,
        const int* __restrict__ gdst,
        __half* __restrict__ like,
        double* __restrict__ acc,   // acc[0]=sum, acc[1]=sumsq
        int E, int Ep) {
    int e0 = (blockIdx.x * blockDim.x + threadIdx.x) * 4;
    float lsum = 0.f, lsq = 0.f;
    if (e0 + 4 <= E) {
        v4i d4 = __builtin_nontemporal_load((const v4i*)(gdst + e0));
        int id[4] = {d4.x, d4.y, d4.z, d4.w};
        unsigned r[4][6];
        #pragma unroll
        for (int j = 0; j < 6; ++j) {
            v4u c = __builtin_nontemporal_load(
                (const v4u*)(srow + (size_t)j * Ep + e0));
            r[0][j] = c.x; r[1][j] = c.y; r[2][j] = c.z; r[3][j] = c.w;
        }
        float dv[4];
        #pragma unroll
        for (int k = 0; k < 4; ++k) {
            const int4* row = (const int4*)(hd + (size_t)id[k] * 8);
            union U { int4 v; unsigned u[4]; };
            U b0{row[0]};
            int2 b1 = ((const int2*)row)[2];
            unsigned bu[6] = {b0.u[0], b0.u[1], b0.u[2], b0.u[3],
                              (unsigned)b1.x, (unsigned)b1.y};
            dv[k] = rowdot12u(r[k], bu);
            lsum += dv[k];
            lsq  = fmaf(dv[k], dv[k], lsq);
        }
        v2u o;
        o.x = h22u(__floats2half2_rn(dv[0], dv[1]));
        o.y = h22u(__floats2half2_rn(dv[2], dv[3]));
        __builtin_nontemporal_store(o, (v2u*)(like + e0));
    } else {
        for (int e = e0; e < E; ++e) {
            const int4* row = (const int4*)(hd + (size_t)gdst[e] * 8);
            union U { int4 v; unsigned u[4]; };
            U b0{row[0]};
            int2 b1 = ((const int2*)row)[2];
            unsigned bu[6] = {b0.u[0], b0.u[1], b0.u[2], b0.u[3],
                              (unsigned)b1.x, (unsigned)b1.y};
            unsigned au[6];
            for (int j = 0; j < 6; ++j) au[j] = srow[(size_t)j * Ep + e];
            float d = rowdot12u(au, bu);
            like[e] = __float2half(d);
            lsum += d;
            lsq  += d * d;
        }
    }
    for (int off = 32; off > 0; off >>= 1) {
        lsum += __shfl_down(lsum, off);
        lsq  += __shfl_down(lsq, off);
    }
    __shared__ float ssum[4], ssq[4];
    int wave = threadIdx.x >> 6;
    int lane = threadIdx.x & 63;
    if (lane == 0) { ssum[wave] = lsum; ssq[wave] = lsq; }
    __syncthreads();
    if (threadIdx.x == 0) {
        float ts = 0.f, tq = 0.f;
        for (int i = 0; i < 4; ++i) { ts += ssum[i]; tq += ssq[i]; }
        atomicAdd(&acc[0], (double)ts);
        atomicAdd(&acc[1], (double)tq);
    }
}

// Fused single-pass fallback (round-5 style) if ws can't hold srow.
__global__ __launch_bounds__(256) void k_dot_fused(
        const __half2* __restrict__ hs,
        const __half2* __restrict__ hd,
        const int* __restrict__ gsrc,
        const int* __restrict__ gdst,
        __half* __restrict__ like,
        double* __restrict__ acc,
        int E) {
    int e0 = (blockIdx.x * blockDim.x + threadIdx.x) * 8;
    float lsum = 0.f, lsq = 0.f;
    if (e0 + 8 <= E) {
        v4i s0 = __builtin_nontemporal_load((const v4i*)(gsrc + e0));
        v4i s1 = __builtin_nontemporal_load((const v4i*)(gsrc + e0 + 4));
        v4i d0 = __builtin_nontemporal_load((const v4i*)(gdst + e0));
        v4i d1 = __builtin_nontemporal_load((const v4i*)(gdst + e0 + 4));
        int is[8] = {s0.x, s0.y, s0.z, s0.w, s1.x, s1.y, s1.z, s1.w};
        int id[8] = {d0.x, d0.y, d0.z, d0.w, d1.x, d1.y, d1.z, d1.w};
        float dv[8];
        #pragma unroll
        for (int k = 0; k < 8; ++k) {
            dv[k] = rowdot((const int4*)(hs + (size_t)is[k] * 8),
                           (const int4*)(hd + (size_t)id[k] * 8));
            lsum += dv[k];
            lsq  = fmaf(dv[k], dv[k], lsq);
        }
        v4u o;
        o.x = h22u(__floats2half2_rn(dv[0], dv[1]));
        o.y = h22u(__floats2half2_rn(dv[2], dv[3]));
        o.z = h22u(__floats2half2_rn(dv[4], dv[5]));
        o.w = h22u(__floats2half2_rn(dv[6], dv[7]));
        __builtin_nontemporal_store(o, (v4u*)(like + e0));
    } else {
        for (int e = e0; e < E; ++e) {
            float d = rowdot((const int4*)(hs + (size_t)gsrc[e] * 8),
                             (const int4*)(hd + (size_t)gdst[e] * 8));
            like[e] = __float2half(d);
            lsum += d;
            lsq  += d * d;
        }
    }
    for (int off = 32; off > 0; off >>= 1) {
        lsum += __shfl_down(lsum, off);
        lsq  += __shfl_down(lsq, off);
    }
    __shared__ float ssum[4], ssq[4];
    int wave = threadIdx.x >> 6;
    int lane = threadIdx.x & 63;
    if (lane == 0) { ssum[wave] = lsum; ssq[wave] = lsq; }
    __syncthreads();
    if (threadIdx.x == 0) {
        float ts = 0.f, tq = 0.f;
        for (int i = 0; i < 4; ++i) { ts += ssum[i]; tq += ssq[i]; }
        atomicAdd(&acc[0], (double)ts);
        atomicAdd(&acc[1], (double)tq);
    }
}

// ---------------------------------------------------------------------------
// K2: fold batch stats + bn affine into (scale, shift).
// ---------------------------------------------------------------------------
__global__ void k_params(const double* __restrict__ acc,
                         const float* __restrict__ bnw,
                         const float* __restrict__ bnb,
                         float* __restrict__ params,
                         int E) {
    double mean = acc[0] / (double)E;
    double var  = acc[1] / (double)E - mean * mean;
    float invstd = rsqrtf((float)var + BN_EPS);
    float scale = bnw[0] * invstd;
    params[0] = scale;
    params[1] = bnb[0] - (float)mean * scale;
}

// ---------------------------------------------------------------------------
// K3: LDS-privatized segment sum, dynamic-LDS bucket (100 KB -> P=4 passes),
// NT streaming loads, slab output via NT stores, no global atomics.
// ---------------------------------------------------------------------------
__global__ __launch_bounds__(512) void k_bucket_scatter(
        const __half* __restrict__ like,
        const int* __restrict__ gsrc,
        const float* __restrict__ params,
        float* __restrict__ slab,   // [(p*G + g) * bucket]
        int E, int G, int bucket) {
    extern __shared__ float sm[];
    const int g  = blockIdx.x;
    const int p  = blockIdx.y;
    const int lo = p * bucket;

    for (int i = threadIdx.x; i < bucket; i += blockDim.x) sm[i] = 0.f;
    __syncthreads();

    const float scale = params[0];
    const float shift = params[1];

    int per = (E + G - 1) / G;
    per = (per + 3) & ~3;
    const int s0 = g * per;
    const int s1 = min(s0 + per, E);

    for (int e = s0 + (int)threadIdx.x * 4; e < s1; e += (int)blockDim.x * 4) {
        if (e + 4 <= s1) {
            v4i n4 = __builtin_nontemporal_load((const v4i*)(gsrc + e));
            v2u l2 = __builtin_nontemporal_load((const v2u*)(like + e));
            float2 fa = __half22float2(u2h2(l2.x));
            float2 fb = __half22float2(u2h2(l2.y));
            unsigned o0 = (unsigned)(n4.x - lo);
            unsigned o1 = (unsigned)(n4.y - lo);
            unsigned o2 = (unsigned)(n4.z - lo);
            unsigned o3 = (unsigned)(n4.w - lo);
            if (o0 < (unsigned)bucket) atomicAdd(&sm[o0], __expf(fmaf(fa.x, scale, shift)));
            if (o1 < (unsigned)bucket) atomicAdd(&sm[o1], __expf(fmaf(fa.y, scale, shift)));
            if (o2 < (unsigned)bucket) atomicAdd(&sm[o2], __expf(fmaf(fb.x, scale, shift)));
            if (o3 < (unsigned)bucket) atomicAdd(&sm[o3], __expf(fmaf(fb.y, scale, shift)));
        } else {
            for (int k = 0; e + k < s1; ++k) {
                unsigned o = (unsigned)(gsrc[e + k] - lo);
                if (o < (unsigned)bucket)
                    atomicAdd(&sm[o], __expf(fmaf(__half2float(like[e + k]), scale, shift)));
            }
        }
    }
    __syncthreads();

    float* dst = slab + ((size_t)p * G + g) * bucket;
    for (int i = threadIdx.x; i < bucket; i += blockDim.x)
        __builtin_nontemporal_store(sm[i], dst + i);
}

// ---------------------------------------------------------------------------
// K3b: fold slabs: denom[n] = sum_g slab[(p(n)*G + g)*bucket + n%bucket]
// ---------------------------------------------------------------------------
__global__ void k_fold(const float* __restrict__ slab,
                       float* __restrict__ denom, int N, int G, int bucket) {
    int n = blockIdx.x * blockDim.x + threadIdx.x;
    if (n >= N) return;
    int p   = n / bucket;
    int off = n - p * bucket;
    const float* s = slab + (size_t)p * G * bucket + off;
    float acc = 0.f;
    for (int g = 0; g < G; ++g)
        acc += __builtin_nontemporal_load(s + (size_t)g * bucket);
    denom[n] = acc;
}

// ---------------------------------------------------------------------------
// K4: out[e] = exp(like*scale+shift) / (1e-12 + denom[gsrc[e]])
// ---------------------------------------------------------------------------
__global__ void k_normalize(const __half* __restrict__ like,
                            const int* __restrict__ gsrc,
                            const float* __restrict__ params,
                            const float* __restrict__ denom,
                            float* __restrict__ out,
                            int E) {
    const float scale = params[0];
    const float shift = params[1];
    int e = (blockIdx.x * blockDim.x + threadIdx.x) * 4;
    if (e + 4 <= E) {
        v4i n4 = __builtin_nontemporal_load((const v4i*)(gsrc + e));
        v2u l2 = __builtin_nontemporal_load((const v2u*)(like + e));
        float2 fa = __half22float2(u2h2(l2.x));
        float2 fb = __half22float2(u2h2(l2.y));
        v4f o;
        o.x = __expf(fmaf(fa.x, scale, shift)) / (1e-12f + denom[n4.x]);
        o.y = __expf(fmaf(fa.y, scale, shift)) / (1e-12f + denom[n4.y]);
        o.z = __expf(fmaf(fb.x, scale, shift)) / (1e-12f + denom[n4.z]);
        o.w = __expf(fmaf(fb.y, scale, shift)) / (1e-12f + denom[n4.w]);
        __builtin_nontemporal_store(o, (v4f*)(out + e));
    } else {
        for (; e < E; ++e)
            out[e] = __expf(fmaf(__half2float(like[e]), scale, shift)) /
                     (1e-12f + denom[gsrc[e]]);
    }
}

// Fallback (agent-scope atomics) if ws can't hold the slab.
__global__ void k_exp_scatter_agent(const __half* __restrict__ like,
                                    const int* __restrict__ gsrc,
                                    const float* __restrict__ params,
                                    float* __restrict__ denom,
                                    int E) {
    float scale = params[0];
    float shift = params[1];
    for (int e = blockIdx.x * blockDim.x + threadIdx.x; e < E;
         e += gridDim.x * blockDim.x) {
        atomicAdd(&denom[gsrc[e]],
                  __expf(fmaf(__half2float(like[e]), scale, shift)));
    }
}

extern "C" void kernel_launch(void* const* d_in, const int* in_sizes, int n_in,
                              void* d_out, int out_size, void* d_ws, size_t ws_size,
                              hipStream_t stream) {
    const float* src_emb = (const float*)d_in[0];
    const float* dst_emb = (const float*)d_in[1];
    const float* bnw     = (const float*)d_in[2];
    const float* bnb     = (const float*)d_in[3];
    const int*   gsrc    = (const int*)d_in[4];
    const int*   gdst    = (const int*)d_in[5];

    const int E = in_sizes[4];           // 3,200,000 edges
    const int N = in_sizes[0] / 12;      // 100,000 nodes
    float* out = (float*)d_out;

    const int bucket = 25000;            // 100 KB dynamic LDS
    const int P = (N + bucket - 1) / bucket;   // 4 passes
    const int Ep = (E + 3) & ~3;         // plane stride (4-aligned)

    // workspace layout (64B-aligned regions):
    //   acc(16)|params(16)|pad | like(2E) | denom(4N) | hs(32N) | hd(32N) |
    //   shared region: max(srow 24*Ep, slab P*G*bucket*4) (disjoint lifetimes)
    char* ws = (char*)d_ws;
    double*  acc    = (double*)ws;
    float*   params = (float*)(ws + 16);
    size_t   off    = 64;
    __half*  like   = (__half*)(ws + off);  off += ((size_t)E * 2 + 63) & ~(size_t)63;
    float*   denom  = (float*)(ws + off);   off += ((size_t)N * 4 + 63) & ~(size_t)63;
    __half2* hs     = (__half2*)(ws + off); off += ((size_t)N * 32 + 63) & ~(size_t)63;
    __half2* hd     = (__half2*)(ws + off); off += ((size_t)N * 32 + 63) & ~(size_t)63;
    unsigned* srow  = (unsigned*)(ws + off);
    float*    slab  = (float*)(ws + off);

    size_t rem = (ws_size > off) ? ws_size - off : 0;
    size_t srow_bytes = (size_t)Ep * 24;
    bool split = (rem >= srow_bytes);

    int G = 0;
    for (int cand = 64; cand >= 8; cand >>= 1) {
        if ((size_t)P * cand * bucket * 4 <= rem) { G = cand; break; }
    }

    const int block = 256;

    hipMemsetAsync(ws, 0, 32, stream);

    k_pack_half<<<(N + block - 1) / block, block, 0, stream>>>(src_emb, hs, N);
    k_pack_half<<<(N + block - 1) / block, block, 0, stream>>>(dst_emb, hd, N);

    if (split) {
        int t4 = (E + 3) / 4;
        int b4 = (t4 + block - 1) / block;
        k_gather_src<<<b4, block, 0, stream>>>(hs, gsrc, srow, E, Ep);
        k_dot_stats<<<b4, block, 0, stream>>>(hd, srow, gdst, like, acc, E, Ep);
    } else {
        int t8 = (E + 7) / 8;
        int b8 = (t8 + block - 1) / block;
        k_dot_fused<<<b8, block, 0, stream>>>(hs, hd, gsrc, gdst, like, acc, E);
    }

    k_params<<<1, 1, 0, stream>>>(acc, bnw, bnb, params, E);

    if (G > 0) {
        dim3 grid(G, P);
        k_bucket_scatter<<<grid, 512, (size_t)bucket * 4, stream>>>(
            like, gsrc, params, slab, E, G, bucket);
        k_fold<<<(N + block - 1) / block, block, 0, stream>>>(slab, denom, N,
                                                              G, bucket);
    } else {
        hipMemsetAsync(denom, 0, (size_t)N * 4, stream);
        int blocks = min((E + block - 1) / block, 4096);
        k_exp_scatter_agent<<<blocks, block, 0, stream>>>(like, gsrc, params,
                                                          denom, E);
    }

    k_normalize<<<(E / 4 + block - 1) / block, block, 0, stream>>>(
        like, gsrc, params, denom, out, E);
}